// Round 1
// 232.945 us; speedup vs baseline: 1.0107x; 1.0107x over previous
//
#include <hip/hip_runtime.h>

// SparseActivation: per row of D=2048 fp32, keep top K=204 by |x|, scale by D/K.
// One WAVE per row, 32 abs-values/lane in registers + sign bits packed into a
// single VGPR. Exact K-th largest via BRACKET BISECTION on bit patterns:
// maintain lo (count>=K) / hi (count<K); any interior probe is a valid step,
// so we warm-start with distribution-informed probes near the expected K-th
// value (~1.648 for N(0,1), k/n=0.1) and ladder outward. Exactness holds for
// ANY input: every bracket update is backed by an exact count; when the
// bracket closes to hi==lo+1, lo IS the exact K-th pattern and boundary ties
// are resolved by lowest-global-index ranking (matches lax.top_k stability).
// This cuts expected counting passes from ~18 (prefix-radix from bit 30) to
// ~7-8, each pass being 64 VALU + one 6-op DPP reduce + scalar branch.

constexpr int D_DIM = 2048;
constexpr int K_SEL = 204;     // int(2048 * 0.1)
constexpr int NT    = 256;     // 4 waves/block, one row per wave
constexpr int EPL   = 32;      // elements per lane

typedef float f32x4 __attribute__((ext_vector_type(4)));

// Full-wave64 integer sum via DPP; returns total (uniform, via readlane 63).
__device__ __forceinline__ int dpp_reduce_add(int x) {
    x += __builtin_amdgcn_update_dpp(0, x, 0x111, 0xF, 0xF, true);  // row_shr:1
    x += __builtin_amdgcn_update_dpp(0, x, 0x112, 0xF, 0xF, true);  // row_shr:2
    x += __builtin_amdgcn_update_dpp(0, x, 0x114, 0xF, 0xF, true);  // row_shr:4
    x += __builtin_amdgcn_update_dpp(0, x, 0x118, 0xF, 0xF, true);  // row_shr:8
    x += __builtin_amdgcn_update_dpp(0, x, 0x142, 0xA, 0xF, false); // row_bcast:15
    x += __builtin_amdgcn_update_dpp(0, x, 0x143, 0xC, 0xF, false); // row_bcast:31
    return __builtin_amdgcn_readlane(x, 63);
}

// Exact wave-wide count of elements with abs-pattern >= test.
__device__ __forceinline__ int wave_count_ge(const unsigned (&a)[EPL],
                                             unsigned test) {
    int c0 = 0, c1 = 0, c2 = 0, c3 = 0;
#pragma unroll
    for (int j = 0; j < EPL; j += 4) {
        c0 += (a[j + 0] >= test) ? 1 : 0;
        c1 += (a[j + 1] >= test) ? 1 : 0;
        c2 += (a[j + 2] >= test) ? 1 : 0;
        c3 += (a[j + 3] >= test) ? 1 : 0;
    }
    return dpp_reduce_add((c0 + c1) + (c2 + c3));
}

__global__ __launch_bounds__(NT) void sparse_topk_kernel(const float* __restrict__ x,
                                                         float* __restrict__ out) {
    const int wave = threadIdx.x >> 6;
    const int lane = threadIdx.x & 63;
    const long long row = (long long)blockIdx.x * 4 + wave;
    const float* xr = x + row * D_DIM;
    float* outr = out + row * D_DIM;

    // Element (b, lane, e): global index = 256*b + 4*lane + e, j = 4*b + e.
    unsigned a[EPL];       // abs bit patterns (bit31 == 0)
    unsigned signs = 0u;   // sign bit of element j in bit j
    const float4* xp = reinterpret_cast<const float4*>(xr);
#pragma unroll
    for (int b = 0; b < 8; ++b) {
        const float4 f = xp[b * 64 + lane];
        const unsigned w0 = __float_as_uint(f.x), w1 = __float_as_uint(f.y);
        const unsigned w2 = __float_as_uint(f.z), w3 = __float_as_uint(f.w);
        a[4 * b + 0] = w0 & 0x7fffffffu; signs |= (w0 >> 31) << (4 * b + 0);
        a[4 * b + 1] = w1 & 0x7fffffffu; signs |= (w1 >> 31) << (4 * b + 1);
        a[4 * b + 2] = w2 & 0x7fffffffu; signs |= (w2 >> 31) << (4 * b + 2);
        a[4 * b + 3] = w3 & 0x7fffffffu; signs |= (w3 >> 31) << (4 * b + 3);
    }

    const float scale = 2048.0f / 204.0f;

    // Bracket invariant: count(>= lo) >= K > count(>= hi).
    // lo=0 counts all 2048 (>=K); hi=2^31 counts none (<K; abs <= 0x7F800000).
    unsigned lo = 0u, hi = 0x80000000u;
    unsigned thr = 0u;
    bool done = false;

    // ---- Warm-start probe ladder (speed heuristic only; exact regardless) --
    // For N(0,1), the K-th largest |x| of a 2048-row is ~N(1.6458, 0.0322^2).
    {
        const int c = wave_count_ge(a, 0x3FD30000u);            // 1.6484375
        if (c == K_SEL) { thr = 0x3FD30000u; done = true; }
        else if (c > K_SEL) lo = 0x3FD30000u; else hi = 0x3FD30000u;
    }
    if (!done) {
        const unsigned p2 = (lo != 0u) ? 0x3FD60000u             // 1.671875
                                       : 0x3FD00000u;            // 1.625
        const int c = wave_count_ge(a, p2);
        if (c == K_SEL) { thr = p2; done = true; }
        else if (c > K_SEL) lo = p2; else hi = p2;
    }
    if (!done) {
        unsigned p3 = 0u;
        if (hi == 0x80000000u)      p3 = 0x3FE00000u;            // 1.75 (cap)
        else if (lo == 0u)          p3 = 0x3FC80000u;            // 1.5625 (floor)
        if (p3 != 0u) {
            const int c = wave_count_ge(a, p3);
            if (c == K_SEL) { thr = p3; done = true; }
            else if (c > K_SEL) lo = p3; else hi = p3;
        }
    }
    if (!done && lo == 0u) {   // very rare: K-th below 1.5625
        const int c = wave_count_ge(a, 0x3F800000u);             // 1.0
        if (c == K_SEL) { thr = 0x3F800000u; done = true; }
        else if (c > K_SEL) lo = 0x3F800000u; else hi = 0x3F800000u;
    }

    // ---- Integer bisection of the bracket; early exit at exact count K. ----
#pragma unroll 1
    while (!done && (hi - lo) > 1u) {
        const unsigned mid = (lo + hi) >> 1;   // lo < mid < hi guaranteed
        const int c = wave_count_ge(a, mid);
        if (c == K_SEL) { thr = mid; done = true; }
        else if (c > K_SEL) lo = mid; else hi = mid;
    }

    float v[EPL];  // output values (epilogue only)

    if (done) {
        // Exact top-K set == {a >= thr}; no tie handling needed.
#pragma unroll
        for (int j = 0; j < EPL; ++j) {
            const float val =
                __uint_as_float(a[j] | (((signs >> j) & 1u) << 31)) * scale;
            v[j] = (a[j] >= thr) ? val : 0.0f;
        }
    } else {
        // Bracket closed: lo is the exact K-th largest pattern
        // (count(>=lo) > K since lo never hit count==K, count(>lo)=count(>=hi)<K).
        const unsigned T = lo;
        int ge_pack = 0;
#pragma unroll
        for (int j = 0; j < EPL; ++j) {
            ge_pack += (a[j] > T) ? 1 : 0;
            ge_pack += (a[j] == T) ? (1 << 16) : 0;
        }
        const int tot = dpp_reduce_add(ge_pack);
        const int cnt_gt = tot & 0xFFFF;
        const int neq = tot >> 16;
        const int r = K_SEL - cnt_gt;   // equals to keep (1 <= r <= neq)

        if (neq == r) {
#pragma unroll
            for (int j = 0; j < EPL; ++j) {
                const float val =
                    __uint_as_float(a[j] | (((signs >> j) & 1u) << 31)) * scale;
                v[j] = (a[j] >= T) ? val : 0.0f;
            }
        } else {
            // Rare: among ==T keep the r with lowest global index
            // (matches lax.top_k stability). Rank via equality ballots.
            const unsigned long long lt =
                (lane == 0) ? 0ull : (~0ull >> (64 - lane));
            int base = 0;  // equals in blocks b' < b
            for (int b = 0; b < 8; ++b) {
                unsigned long long m[4];
#pragma unroll
                for (int e = 0; e < 4; ++e) m[e] = __ballot(a[4 * b + e] == T);
                int cm = 0;  // equals in this block from lanes < lane
#pragma unroll
                for (int e = 0; e < 4; ++e) cm += __popcll(m[e] & lt);
                int partial = 0;  // equals: same lane, e' < e
#pragma unroll
                for (int e = 0; e < 4; ++e) {
                    const int j = 4 * b + e;
                    const int rank = base + cm + partial;
                    const bool eq = (a[j] == T);
                    const bool sel = (a[j] > T) || (eq && rank < r);
                    const float val =
                        __uint_as_float(a[j] | (((signs >> j) & 1u) << 31)) * scale;
                    v[j] = sel ? val : 0.0f;
                    partial += (int)((m[e] >> lane) & 1ull);
                }
#pragma unroll
                for (int e = 0; e < 4; ++e) base += __popcll(m[e]);
            }
        }
    }

    // Nontemporal stores: output is write-once streaming; don't evict the
    // L3-resident input with 134 MB of output lines.
    f32x4* op = reinterpret_cast<f32x4*>(outr);
#pragma unroll
    for (int b = 0; b < 8; ++b) {
        f32x4 w;
        w.x = v[4 * b + 0]; w.y = v[4 * b + 1];
        w.z = v[4 * b + 2]; w.w = v[4 * b + 3];
        __builtin_nontemporal_store(w, op + b * 64 + lane);
    }
}

extern "C" void kernel_launch(void* const* d_in, const int* in_sizes, int n_in,
                              void* d_out, int out_size, void* d_ws, size_t ws_size,
                              hipStream_t stream) {
    const float* x = (const float*)d_in[0];
    float* out = (float*)d_out;
    const int rows = in_sizes[0] / D_DIM;            // 16384
    sparse_topk_kernel<<<rows / 4, NT, 0, stream>>>(x, out);
}